// Round 18
// baseline (263.572 us; speedup 1.0000x reference)
//
#include <hip/hip_runtime.h>
#include <math.h>

// Problem constants
constexpr int B_  = 8;
constexpr int NU  = 256;
constexpr int NA  = 256;
constexpr int UD  = 128;
constexpr int ED  = 64;
constexpr int H   = 8;
constexpr int HD  = 64;
constexpr int HID = 512;
constexpr float SLOPE = 0.2f;
constexpr float SCALE = 0.125f;

// ws layout (floats)
constexpr size_t WS_UT    = 0;          // [B][512][256]  (user@Wu)^T : UT[b][j][u]
constexpr size_t WS_AT    = 1048576;    // [B][512][256]  bf16 (ant@Wa)^T : AT16[b][j][a]
constexpr size_t WS_UBASE = 2097152;    // [B][NU][512]   user@Wres
constexpr size_t WS_ALPHA = 3145728;    // [B][NU][NA][H] softmax weights
constexpr size_t WS_WET32 = 7340032;    // [512][64] fp32  WeT[j][e] = We[j>>6][e][j&63]
constexpr size_t WS_WET16 = 7372800;    // [512][64] bf16 (as ushort), same layout

typedef __attribute__((ext_vector_type(8))) short short8v;  // 8 bf16
typedef __attribute__((ext_vector_type(4))) float f32x4;

static __device__ __forceinline__ unsigned short f2bf(float f) {
  unsigned int u = __float_as_uint(f);
  unsigned int r = (u + 0x7fffu + ((u >> 16) & 1u)) >> 16;   // RNE
  return (unsigned short)r;
}

// LDS-only block barrier: waits LDS ops (lgkmcnt) but does NOT drain vmcnt.
static __device__ __forceinline__ void block_sync_lds() {
  asm volatile("s_waitcnt lgkmcnt(0)" ::: "memory");
  __builtin_amdgcn_sched_barrier(0);
  __builtin_amdgcn_s_barrier();
  __builtin_amdgcn_sched_barrier(0);
}

// 16-lane butterfly sum entirely on the VALU via DPP (no LDS-pipe ops).
template <int CTRL>
static __device__ __forceinline__ float dpp_add(float v) {
  return v + __int_as_float(__builtin_amdgcn_mov_dpp(
                 __float_as_int(v), CTRL, 0xF, 0xF, false));
}
static __device__ __forceinline__ float red16_dpp(float v) {
  v = dpp_add<0xB1>(v);    // quad_perm [1,0,3,2] : xor 1
  v = dpp_add<0x4E>(v);    // quad_perm [2,3,0,1] : xor 2
  v = dpp_add<0x141>(v);   // row_half_mirror     : xor 7
  v = dpp_add<0x140>(v);   // row_mirror          : xor 15
  return v;
}

// ---------------------------------------------------------------------------
// Kernel A: projections + WeT precompute. grid (512, 4), 256 thr.
// job 0: UT = (user@Wu)^T ; job 1: AT16 = bf16 (ant@Wa)^T ; job 2: ubase
// job 3 (blocks 0..7 only): WeT fp32+bf16
// ---------------------------------------------------------------------------
__global__ __launch_bounds__(256) void prep_kernel(
    const float* __restrict__ user, const float* __restrict__ ant,
    const float* __restrict__ Wu, const float* __restrict__ Wa,
    const float* __restrict__ Wres, const float* __restrict__ We,
    float* __restrict__ ws)
{
  const int job = blockIdx.y;
  const int t   = threadIdx.x;
  __shared__ float xs[ED * HD];   // 16 KB (job 3 uses all; jobs 0-2 use 2 KB)

  if (job == 3) {
    const int h = blockIdx.x;
    if (h >= H) return;
    const float4* src = (const float4*)(We + (size_t)h * ED * HD);
    #pragma unroll
    for (int i = 0; i < 4; ++i) ((float4*)xs)[i * 256 + t] = src[i * 256 + t];
    __syncthreads();
    const int d = t >> 2, q = t & 3;
    float* WeTf = ws + WS_WET32;
    unsigned short* WeT16 = (unsigned short*)(ws + WS_WET16);
    const size_t jrow = (size_t)(h * HD + d) * ED;
    #pragma unroll
    for (int k = 0; k < 16; ++k) {
      const int e = q * 16 + k;
      float v = xs[e * HD + d];
      WeTf[jrow + e]  = v;
      WeT16[jrow + e] = f2bf(v);
    }
    return;
  }

  const int r0  = blockIdx.x * 4;
  const int b   = r0 >> 8, lr = r0 & 255;

  const float* X = (job == 1) ? ant : user;
  const float* W = (job == 0) ? Wu : (job == 1) ? Wa : Wres;

  #pragma unroll
  for (int i = 0; i < 2; ++i) {
    int idx = i * 256 + t;
    xs[(idx >> 7) * UD + (idx & 127)] =
        X[(size_t)(r0 + (idx >> 7)) * UD + (idx & 127)];
  }
  __syncthreads();

  const int j0 = 2 * t;
  const float* wp;
  int wstride;
  if (job < 2) { wp = W + (size_t)(j0 >> 6) * (UD * HD) + (j0 & 63); wstride = HD; }
  else         { wp = W + j0;                                        wstride = HID; }

  float2 acc[4];
  #pragma unroll
  for (int r = 0; r < 4; ++r) acc[r] = make_float2(0.f, 0.f);

  for (int k = 0; k < UD; ++k) {
    float2 w = *(const float2*)(wp + (size_t)k * wstride);
    #pragma unroll
    for (int r = 0; r < 4; ++r) {
      float x = xs[r * UD + k];
      acc[r].x += x * w.x;
      acc[r].y += x * w.y;
    }
  }

  if (job == 0) {
    float* T = ws + WS_UT;
    float4 w0 = make_float4(acc[0].x, acc[1].x, acc[2].x, acc[3].x);
    float4 w1 = make_float4(acc[0].y, acc[1].y, acc[2].y, acc[3].y);
    *(float4*)(T + ((size_t)b * HID + j0)     * 256 + lr) = w0;
    *(float4*)(T + ((size_t)b * HID + j0 + 1) * 256 + lr) = w1;
  } else if (job == 1) {
    unsigned short* T16 = (unsigned short*)(ws + WS_AT);
    ushort4 s0 = make_ushort4(f2bf(acc[0].x), f2bf(acc[1].x),
                              f2bf(acc[2].x), f2bf(acc[3].x));
    ushort4 s1 = make_ushort4(f2bf(acc[0].y), f2bf(acc[1].y),
                              f2bf(acc[2].y), f2bf(acc[3].y));
    *(ushort4*)(T16 + ((size_t)b * HID + j0)     * 256 + lr) = s0;
    *(ushort4*)(T16 + ((size_t)b * HID + j0 + 1) * 256 + lr) = s1;
  } else {
    float* outp = ws + WS_UBASE;
    #pragma unroll
    for (int r = 0; r < 4; ++r)
      *(float2*)(outp + (size_t)(r0 + r) * HID + j0) = acc[r];
  }
}

// ---------------------------------------------------------------------------
// Kernel B: per (b,u). 512 threads = 8 waves; wave w = head w.
// 8 x 32-antenna tiles, bf16 A-panel acc-init (halves the dominant L2
// stream), LDS staging + double buffer, AT loads issued before edge
// prefetch, LDS-only barriers, DPP score reduction, defer-max softmax.
// ---------------------------------------------------------------------------
__global__ __launch_bounds__(512, 4) void score_user_kernel(
    const float* __restrict__ edge, const float* __restrict__ av,
    float* __restrict__ ws, float* __restrict__ out)
{
  const int bid = blockIdx.x;          // b*NU + u
  const int b = bid >> 8, u = bid & 255;
  const int t = threadIdx.x;

  __shared__ __align__(16) short ebuf[2][32 * ED];  // 2 x 4 KB bf16, swizzled
  __shared__ float sc[NA * 9];                      // exp(score) per [a][h]
  __shared__ float gu[HID];
  __shared__ float sinv[H];

  const float* UT = ws + WS_UT;

  const int w    = t >> 6;          // wave = head
  const int lane = t & 63;
  const int l16  = lane & 15;
  const int kgrp = lane >> 4;

  // hoist We fragments (bf16), U cols, av (pre-scaled)
  short8v wf[4][2];
  float   ucol[4];
  float   avv[4];
  const unsigned short* WeT16 = (const unsigned short*)(ws + WS_WET16);
  #pragma unroll
  for (int n = 0; n < 4; ++n) {
    const int j = 64 * w + 16 * n + l16;
    #pragma unroll
    for (int c = 0; c < 2; ++c)
      wf[n][c] = *(const short8v*)(WeT16 + (size_t)j * ED + c * 32 + kgrp * 8);
    ucol[n] = UT[((size_t)b * HID + j) * 256 + u];
    avv[n]  = av[j] * SCALE;
  }

  // staging geometry
  const float4* ep = (const float4*)(edge + (size_t)bid * NA * ED);
  const int srow = t >> 4, sc4 = t & 15;
  const int sbyte = (srow * 128 + sc4 * 8) ^ ((srow & 7) << 4);
  float4 v = ep[t];   // tile 0 edge prefetch

  const unsigned short* AT16 = (const unsigned short*)(ws + WS_AT);
  const unsigned short* ATbase = AT16 + (size_t)b * HID * 256 + kgrp * 4;

  float lsum = 0.f;
  float O[4] = {0.f, 0.f, 0.f, 0.f};

  for (int t8 = 0; t8 < 8; ++t8) {
    const int cur = t8 & 1;
    {
      unsigned int lo, hi;
      asm("v_cvt_pk_bf16_f32 %0, %1, %2" : "=v"(lo) : "v"(v.x), "v"(v.y));
      asm("v_cvt_pk_bf16_f32 %0, %1, %2" : "=v"(hi) : "v"(v.z), "v"(v.w));
      *(uint2*)((char*)ebuf[cur] + sbyte) = make_uint2(lo, hi);
    }

    // acc init = A loads (bf16, L2) issued BEFORE the edge prefetch
    const int a0 = t8 * 32;
    f32x4 acc[2][4];
    #pragma unroll
    for (int m = 0; m < 2; ++m)
      #pragma unroll
      for (int n = 0; n < 4; ++n) {
        const int j = 64 * w + 16 * n + l16;
        uint2 d = *(const uint2*)(ATbase + (size_t)j * 256 + a0 + m * 16);
        f32x4 vv;
        vv[0] = __uint_as_float(d.x << 16);
        vv[1] = __uint_as_float(d.x & 0xffff0000u);
        vv[2] = __uint_as_float(d.y << 16);
        vv[3] = __uint_as_float(d.y & 0xffff0000u);
        acc[m][n] = vv;
      }

    __builtin_amdgcn_sched_barrier(0);   // pin: AT loads issue before edge

    if (t8 < 7) v = ep[(t8 + 1) * 512 + t];   // edge prefetch next tile (HBM)

    block_sync_lds();   // LDS-only barrier: no vmcnt drain

    // A-fragments from LDS
    short8v af[2][2];
    #pragma unroll
    for (int m = 0; m < 2; ++m) {
      #pragma unroll
      for (int c = 0; c < 2; ++c) {
        int row = m * 16 + l16;
        int byte = (row * 128 + (c * 32 + kgrp * 8) * 2) ^ ((row & 7) << 4);
        af[m][c] = *(const short8v*)((const char*)ebuf[cur] + byte);
      }
    }

    #pragma unroll
    for (int c = 0; c < 2; ++c)
      #pragma unroll
      for (int m = 0; m < 2; ++m)
        #pragma unroll
        for (int n = 0; n < 4; ++n)
          acc[m][n] = __builtin_amdgcn_mfma_f32_16x16x32_bf16(
              af[m][c], wf[n][c], acc[m][n], 0, 0, 0);

    // epilogue: leaky(acc+U).av, DPP butterfly, exp (defer-max), accumulate
    #pragma unroll
    for (int m = 0; m < 2; ++m) {
      #pragma unroll
      for (int q = 0; q < 4; ++q) {
        float h0 = 0.f;
        #pragma unroll
        for (int n = 0; n < 4; ++n) {
          float s = acc[m][n][q] + ucol[n];
          float sl = fmaxf(s, SLOPE * s);    // leaky for 0<slope<1
          h0 = fmaf(sl, avv[n], h0);
        }
        h0 = red16_dpp(h0);               // all 16 lanes get the sum, VALU-only
        float e = __expf(h0);
        lsum += e;
        if (l16 == 0) sc[(a0 + m * 16 + kgrp * 4 + q) * 9 + w] = e;
        #pragma unroll
        for (int n = 0; n < 4; ++n) O[n] += e * acc[m][n][q];
      }
    }
  }

  // final reductions across kgrp
  lsum += __shfl_xor(lsum, 16);
  lsum += __shfl_xor(lsum, 32);
  #pragma unroll
  for (int n = 0; n < 4; ++n) {
    O[n] += __shfl_xor(O[n], 16);
    O[n] += __shfl_xor(O[n], 32);
  }
  const float inv = 1.0f / lsum;

  if (lane == 0) sinv[w] = inv;
  if (kgrp == 0) {
    #pragma unroll
    for (int n = 0; n < 4; ++n) gu[w * 64 + n * 16 + l16] = O[n] * inv;
  }
  __syncthreads();

  // alpha scatter -> ws [b][u][a][h]  (fully coalesced sequential stores)
  {
    float* ag = ws + WS_ALPHA + (size_t)bid * (NA * H);
    #pragma unroll
    for (int i = 0; i < 4; ++i) {
      int idx = i * 512 + t;
      int a = idx >> 3, hh = idx & 7;
      ag[idx] = sc[a * 9 + hh] * sinv[hh];
    }
  }
  out[(size_t)bid * HID + t] = gu[t] + ws[WS_UBASE + (size_t)bid * HID + t];
}

// ---------------------------------------------------------------------------
// Kernel C: per (b, a-quad). 512 threads = 8 waves (wave = head).
// alpha layout [b][u][a][h]: per-u 128B contiguous segments.
// Pass 1 is 2-deep software-pipelined.
// ---------------------------------------------------------------------------
__global__ __launch_bounds__(512, 4) void ant_kernel(
    const float* __restrict__ edge, float* __restrict__ ws,
    float* __restrict__ out)
{
  const int bid = blockIdx.x;          // b*64 + aq
  const int b = bid >> 6, a0 = (bid & 63) * 4;
  const int t = threadIdx.x;
  const int w = t >> 6;                // wave = head
  const int lane = t & 63;

  __shared__ float plds[NU * 36];      // 36 KB: [u][h*4 + a], stride 36 (pad)
  __shared__ float galds[4 * H * ED];  // 8 KB : [a][h][e]

  // ---- stage alpha from [b][u][a0..a0+3][h] -> plds[u][h][a] ----
  {
    const float4* ag4 = (const float4*)(ws + WS_ALPHA) +
                        ((size_t)b * NU * NA * H) / 4 + a0 * 2;
    #pragma unroll
    for (int r = 0; r < 4; ++r) {
      int idx4 = r * 512 + t;
      int uu = idx4 >> 3, f = idx4 & 7;     // 8 float4 per u: a=f>>1, hq=f&1
      float4 vv = ag4[(size_t)uu * (NA * H / 4) + f];
      float* dst = plds + uu * 36 + (f & 1) * 16 + (f >> 1);
      dst[0]  = vv.x;
      dst[4]  = vv.y;
      dst[8]  = vv.z;
      dst[12] = vv.w;
    }
  }
  __syncthreads();

  // ---- pass 1: g accumulation, quarter-wave (u_loc, e4), pipelined ----
  const int u_loc = lane >> 4, e4 = lane & 15;
  float4 g[4] = {{0,0,0,0},{0,0,0,0},{0,0,0,0},{0,0,0,0}};

  {
    const float* ebase0 = edge + (((size_t)b * NU) * NA + a0) * ED + e4 * 4;

    // prologue: prefetch u-group 0
    float4 ce0, ce1, ce2, ce3, cp;
    {
      const float* eb = ebase0 + (size_t)u_loc * (NA * ED);
      ce0 = *(const float4*)(eb);
      ce1 = *(const float4*)(eb + ED);
      ce2 = *(const float4*)(eb + 2 * ED);
      ce3 = *(const float4*)(eb + 3 * ED);
      cp  = *(const float4*)(plds + u_loc * 36 + w * 4);
    }

    for (int u0 = 0; u0 < NU; u0 += 4) {
      // prefetch next group (clamped on last iteration; harmless reload)
      const int un = (u0 + 4 < NU ? u0 + 4 : u0) + u_loc;
      const float* eb = ebase0 + (size_t)un * (NA * ED);
      float4 ne0 = *(const float4*)(eb);
      float4 ne1 = *(const float4*)(eb + ED);
      float4 ne2 = *(const float4*)(eb + 2 * ED);
      float4 ne3 = *(const float4*)(eb + 3 * ED);
      float4 np  = *(const float4*)(plds + un * 36 + w * 4);

      g[0].x += cp.x * ce0.x; g[0].y += cp.x * ce0.y; g[0].z += cp.x * ce0.z; g[0].w += cp.x * ce0.w;
      g[1].x += cp.y * ce1.x; g[1].y += cp.y * ce1.y; g[1].z += cp.y * ce1.z; g[1].w += cp.y * ce1.w;
      g[2].x += cp.z * ce2.x; g[2].y += cp.z * ce2.y; g[2].z += cp.z * ce2.z; g[2].w += cp.z * ce2.w;
      g[3].x += cp.w * ce3.x; g[3].y += cp.w * ce3.y; g[3].z += cp.w * ce3.z; g[3].w += cp.w * ce3.w;

      ce0 = ne0; ce1 = ne1; ce2 = ne2; ce3 = ne3; cp = np;
    }
  }
  // merge across quarter-waves (u_loc)
  #pragma unroll
  for (int al = 0; al < 4; ++al) {
    g[al].x += __shfl_xor(g[al].x, 16); g[al].x += __shfl_xor(g[al].x, 32);
    g[al].y += __shfl_xor(g[al].y, 16); g[al].y += __shfl_xor(g[al].y, 32);
    g[al].z += __shfl_xor(g[al].z, 16); g[al].z += __shfl_xor(g[al].z, 32);
    g[al].w += __shfl_xor(g[al].w, 16); g[al].w += __shfl_xor(g[al].w, 32);
  }
  if (u_loc == 0) {
    #pragma unroll
    for (int al = 0; al < 4; ++al)
      *(float4*)(galds + (al * H + w) * ED + e4 * 4) = g[al];
  }

  // ---- pass 2: pu accumulation (thread t = output col j) ----
  float pu[4] = {0.f, 0.f, 0.f, 0.f};
  {
    const float* UTj = ws + WS_UT + ((size_t)b * HID + t) * 256;
    for (int u0 = 0; u0 < NU; u0 += 4) {
      float4 U4 = *(const float4*)(UTj + u0);
      float4 p0 = *(const float4*)(plds + (u0 + 0) * 36 + w * 4);
      float4 p1 = *(const float4*)(plds + (u0 + 1) * 36 + w * 4);
      float4 p2 = *(const float4*)(plds + (u0 + 2) * 36 + w * 4);
      float4 p3 = *(const float4*)(plds + (u0 + 3) * 36 + w * 4);
      pu[0] += p0.x*U4.x + p1.x*U4.y + p2.x*U4.z + p3.x*U4.w;
      pu[1] += p0.y*U4.x + p1.y*U4.y + p2.y*U4.z + p3.y*U4.w;
      pu[2] += p0.z*U4.x + p1.z*U4.y + p2.z*U4.z + p3.z*U4.w;
      pu[3] += p0.w*U4.x + p1.w*U4.y + p2.w*U4.z + p3.w*U4.w;
    }
  }
  __syncthreads();   // galds ready

  // ---- projection + store ----
  {
    const float* wrow = ws + WS_WET32 + (size_t)t * ED;
    float o[4] = {pu[0], pu[1], pu[2], pu[3]};
    for (int e0 = 0; e0 < ED; e0 += 4) {
      float4 wv = *(const float4*)(wrow + e0);
      #pragma unroll
      for (int al = 0; al < 4; ++al) {
        float4 ga4 = *(const float4*)(galds + (al * H + w) * ED + e0);
        o[al] += ga4.x*wv.x + ga4.y*wv.y + ga4.z*wv.z + ga4.w*wv.w;
      }
    }
    float* outa = out + (size_t)(B_ * NU) * HID;
    #pragma unroll
    for (int al = 0; al < 4; ++al)
      outa[(size_t)((b * NA) + a0 + al) * HID + t] = o[al];
  }
}

// ---------------------------------------------------------------------------
extern "C" void kernel_launch(void* const* d_in, const int* in_sizes, int n_in,
                              void* d_out, int out_size, void* d_ws, size_t ws_size,
                              hipStream_t stream) {
  const float* user = (const float*)d_in[0];
  const float* ant  = (const float*)d_in[1];
  const float* edge = (const float*)d_in[2];
  const float* Wu   = (const float*)d_in[3];
  const float* Wa   = (const float*)d_in[4];
  const float* We   = (const float*)d_in[5];
  const float* av   = (const float*)d_in[6];
  const float* Wres = (const float*)d_in[7];
  float* out = (float*)d_out;
  float* ws  = (float*)d_ws;

  prep_kernel<<<dim3(512, 4), 256, 0, stream>>>(user, ant, Wu, Wa, Wres, We, ws);
  score_user_kernel<<<dim3(B_ * NU), 512, 0, stream>>>(edge, av, ws, out);
  ant_kernel<<<dim3(B_ * 64), 512, 0, stream>>>(edge, ws, out);
}

// Round 19
// 248.950 us; speedup vs baseline: 1.0587x; 1.0587x over previous
//
#include <hip/hip_runtime.h>
#include <math.h>

// Problem constants
constexpr int B_  = 8;
constexpr int NU  = 256;
constexpr int NA  = 256;
constexpr int UD  = 128;
constexpr int ED  = 64;
constexpr int H   = 8;
constexpr int HD  = 64;
constexpr int HID = 512;
constexpr float SLOPE = 0.2f;
constexpr float SCALE = 0.125f;

// ws layout (floats)
constexpr size_t WS_UT    = 0;          // [B][512][256]  (user@Wu)^T : UT[b][j][u]
constexpr size_t WS_AT    = 1048576;    // [B][512][256]  (ant@Wa)^T  : AT[b][j][a]
constexpr size_t WS_UBASE = 2097152;    // [B][NU][512]   user@Wres
constexpr size_t WS_ALPHA = 3145728;    // [B][NU][NA][H] softmax weights
constexpr size_t WS_WET32 = 7340032;    // [512][64] fp32  WeT[j][e] = We[j>>6][e][j&63]
constexpr size_t WS_WET16 = 7372800;    // [512][64] bf16 (as ushort), same layout

typedef __attribute__((ext_vector_type(8))) short short8v;  // 8 bf16
typedef __attribute__((ext_vector_type(4))) float f32x4;

static __device__ __forceinline__ unsigned short f2bf(float f) {
  unsigned int u = __float_as_uint(f);
  unsigned int r = (u + 0x7fffu + ((u >> 16) & 1u)) >> 16;   // RNE
  return (unsigned short)r;
}

// LDS-only block barrier: waits LDS ops (lgkmcnt) but does NOT drain vmcnt.
static __device__ __forceinline__ void block_sync_lds() {
  asm volatile("s_waitcnt lgkmcnt(0)" ::: "memory");
  __builtin_amdgcn_sched_barrier(0);
  __builtin_amdgcn_s_barrier();
  __builtin_amdgcn_sched_barrier(0);
}

// 16-lane butterfly sum entirely on the VALU via DPP (no LDS-pipe ops).
template <int CTRL>
static __device__ __forceinline__ float dpp_add(float v) {
  return v + __int_as_float(__builtin_amdgcn_mov_dpp(
                 __float_as_int(v), CTRL, 0xF, 0xF, false));
}
static __device__ __forceinline__ float red16_dpp(float v) {
  v = dpp_add<0xB1>(v);    // quad_perm [1,0,3,2] : xor 1
  v = dpp_add<0x4E>(v);    // quad_perm [2,3,0,1] : xor 2
  v = dpp_add<0x141>(v);   // row_half_mirror     : xor 7
  v = dpp_add<0x140>(v);   // row_mirror          : xor 15
  return v;
}

// ---------------------------------------------------------------------------
// Kernel A: projections + WeT precompute. grid (512, 4), 256 thr.
// job 0: UT = (user@Wu)^T ; job 1: AT = (ant@Wa)^T ; job 2: ubase = user@Wres
// job 3 (blocks 0..7 only): WeT fp32+bf16
// ---------------------------------------------------------------------------
__global__ __launch_bounds__(256) void prep_kernel(
    const float* __restrict__ user, const float* __restrict__ ant,
    const float* __restrict__ Wu, const float* __restrict__ Wa,
    const float* __restrict__ Wres, const float* __restrict__ We,
    float* __restrict__ ws)
{
  const int job = blockIdx.y;
  const int t   = threadIdx.x;
  __shared__ float xs[ED * HD];   // 16 KB (job 3 uses all; jobs 0-2 use 2 KB)

  if (job == 3) {
    const int h = blockIdx.x;
    if (h >= H) return;
    const float4* src = (const float4*)(We + (size_t)h * ED * HD);
    #pragma unroll
    for (int i = 0; i < 4; ++i) ((float4*)xs)[i * 256 + t] = src[i * 256 + t];
    __syncthreads();
    const int d = t >> 2, q = t & 3;
    float* WeTf = ws + WS_WET32;
    unsigned short* WeT16 = (unsigned short*)(ws + WS_WET16);
    const size_t jrow = (size_t)(h * HD + d) * ED;
    #pragma unroll
    for (int k = 0; k < 16; ++k) {
      const int e = q * 16 + k;
      float v = xs[e * HD + d];
      WeTf[jrow + e]  = v;
      WeT16[jrow + e] = f2bf(v);
    }
    return;
  }

  const int r0  = blockIdx.x * 4;
  const int b   = r0 >> 8, lr = r0 & 255;

  const float* X = (job == 1) ? ant : user;
  const float* W = (job == 0) ? Wu : (job == 1) ? Wa : Wres;

  #pragma unroll
  for (int i = 0; i < 2; ++i) {
    int idx = i * 256 + t;
    xs[(idx >> 7) * UD + (idx & 127)] =
        X[(size_t)(r0 + (idx >> 7)) * UD + (idx & 127)];
  }
  __syncthreads();

  const int j0 = 2 * t;
  const float* wp;
  int wstride;
  if (job < 2) { wp = W + (size_t)(j0 >> 6) * (UD * HD) + (j0 & 63); wstride = HD; }
  else         { wp = W + j0;                                        wstride = HID; }

  float2 acc[4];
  #pragma unroll
  for (int r = 0; r < 4; ++r) acc[r] = make_float2(0.f, 0.f);

  for (int k = 0; k < UD; ++k) {
    float2 w = *(const float2*)(wp + (size_t)k * wstride);
    #pragma unroll
    for (int r = 0; r < 4; ++r) {
      float x = xs[r * UD + k];
      acc[r].x += x * w.x;
      acc[r].y += x * w.y;
    }
  }

  if (job < 2) {
    float* T = ws + (job == 0 ? WS_UT : WS_AT);
    float4 w0 = make_float4(acc[0].x, acc[1].x, acc[2].x, acc[3].x);
    float4 w1 = make_float4(acc[0].y, acc[1].y, acc[2].y, acc[3].y);
    *(float4*)(T + ((size_t)b * HID + j0)     * 256 + lr) = w0;
    *(float4*)(T + ((size_t)b * HID + j0 + 1) * 256 + lr) = w1;
  } else {
    float* outp = ws + WS_UBASE;
    #pragma unroll
    for (int r = 0; r < 4; ++r)
      *(float2*)(outp + (size_t)(r0 + r) * HID + j0) = acc[r];
  }
}

// ---------------------------------------------------------------------------
// Kernel B: per (b,u). 512 threads = 8 waves; wave w = head w.
// Round-17 structure + bijective XCD swizzle: XCD x owns batch b = x, so
// AT[b] (512 KB) becomes L2-resident on its XCD (acc-init loads turn from
// L3-latency into L2-latency hits).
// ---------------------------------------------------------------------------
__global__ __launch_bounds__(512, 4) void score_user_kernel(
    const float* __restrict__ edge, const float* __restrict__ av,
    float* __restrict__ ws, float* __restrict__ out)
{
  const int bid = (blockIdx.x & 7) * 256 + (blockIdx.x >> 3);  // b*NU + u
  const int b = bid >> 8, u = bid & 255;
  const int t = threadIdx.x;

  __shared__ __align__(16) short ebuf[2][32 * ED];  // 2 x 4 KB bf16, swizzled
  __shared__ float sc[NA * 9];                      // exp(score) per [a][h]
  __shared__ float gu[HID];
  __shared__ float sinv[H];

  const float* UT = ws + WS_UT;
  const float* AT = ws + WS_AT;

  const int w    = t >> 6;          // wave = head
  const int lane = t & 63;
  const int l16  = lane & 15;
  const int kgrp = lane >> 4;

  // hoist We fragments (bf16), U cols, av (pre-scaled)
  short8v wf[4][2];
  float   ucol[4];
  float   avv[4];
  const unsigned short* WeT16 = (const unsigned short*)(ws + WS_WET16);
  #pragma unroll
  for (int n = 0; n < 4; ++n) {
    const int j = 64 * w + 16 * n + l16;
    #pragma unroll
    for (int c = 0; c < 2; ++c)
      wf[n][c] = *(const short8v*)(WeT16 + (size_t)j * ED + c * 32 + kgrp * 8);
    ucol[n] = UT[((size_t)b * HID + j) * 256 + u];
    avv[n]  = av[j] * SCALE;
  }

  // staging geometry
  const float4* ep = (const float4*)(edge + (size_t)bid * NA * ED);
  const int srow = t >> 4, sc4 = t & 15;
  const int sbyte = (srow * 128 + sc4 * 8) ^ ((srow & 7) << 4);
  float4 v = ep[t];   // tile 0 edge prefetch

  const float* ATbase = AT + (size_t)b * HID * 256 + kgrp * 4;

  float lsum = 0.f;
  float O[4] = {0.f, 0.f, 0.f, 0.f};

  for (int t8 = 0; t8 < 8; ++t8) {
    const int cur = t8 & 1;
    {
      unsigned int lo, hi;
      asm("v_cvt_pk_bf16_f32 %0, %1, %2" : "=v"(lo) : "v"(v.x), "v"(v.y));
      asm("v_cvt_pk_bf16_f32 %0, %1, %2" : "=v"(hi) : "v"(v.z), "v"(v.w));
      *(uint2*)((char*)ebuf[cur] + sbyte) = make_uint2(lo, hi);
    }

    // acc init = A loads (L2), issued BEFORE the edge prefetch (vmcnt FIFO)
    const int a0 = t8 * 32;
    f32x4 acc[2][4];
    #pragma unroll
    for (int m = 0; m < 2; ++m)
      #pragma unroll
      for (int n = 0; n < 4; ++n) {
        const int j = 64 * w + 16 * n + l16;
        float4 a4 = *(const float4*)(ATbase + (size_t)j * 256 + a0 + m * 16);
        f32x4 vv; vv[0] = a4.x; vv[1] = a4.y; vv[2] = a4.z; vv[3] = a4.w;
        acc[m][n] = vv;
      }

    __builtin_amdgcn_sched_barrier(0);   // pin: AT loads issue before edge

    if (t8 < 7) v = ep[(t8 + 1) * 512 + t];   // edge prefetch next tile (HBM)

    block_sync_lds();   // LDS-only barrier: no vmcnt drain

    // A-fragments from LDS
    short8v af[2][2];
    #pragma unroll
    for (int m = 0; m < 2; ++m) {
      #pragma unroll
      for (int c = 0; c < 2; ++c) {
        int row = m * 16 + l16;
        int byte = (row * 128 + (c * 32 + kgrp * 8) * 2) ^ ((row & 7) << 4);
        af[m][c] = *(const short8v*)((const char*)ebuf[cur] + byte);
      }
    }

    #pragma unroll
    for (int c = 0; c < 2; ++c)
      #pragma unroll
      for (int m = 0; m < 2; ++m)
        #pragma unroll
        for (int n = 0; n < 4; ++n)
          acc[m][n] = __builtin_amdgcn_mfma_f32_16x16x32_bf16(
              af[m][c], wf[n][c], acc[m][n], 0, 0, 0);

    // epilogue: leaky(acc+U).av, DPP butterfly, exp (defer-max), accumulate
    #pragma unroll
    for (int m = 0; m < 2; ++m) {
      #pragma unroll
      for (int q = 0; q < 4; ++q) {
        float h0 = 0.f;
        #pragma unroll
        for (int n = 0; n < 4; ++n) {
          float s = acc[m][n][q] + ucol[n];
          float sl = fmaxf(s, SLOPE * s);    // leaky for 0<slope<1
          h0 = fmaf(sl, avv[n], h0);
        }
        h0 = red16_dpp(h0);               // all 16 lanes get the sum, VALU-only
        float e = __expf(h0);
        lsum += e;
        if (l16 == 0) sc[(a0 + m * 16 + kgrp * 4 + q) * 9 + w] = e;
        #pragma unroll
        for (int n = 0; n < 4; ++n) O[n] += e * acc[m][n][q];
      }
    }
  }

  // final reductions across kgrp
  lsum += __shfl_xor(lsum, 16);
  lsum += __shfl_xor(lsum, 32);
  #pragma unroll
  for (int n = 0; n < 4; ++n) {
    O[n] += __shfl_xor(O[n], 16);
    O[n] += __shfl_xor(O[n], 32);
  }
  const float inv = 1.0f / lsum;

  if (lane == 0) sinv[w] = inv;
  if (kgrp == 0) {
    #pragma unroll
    for (int n = 0; n < 4; ++n) gu[w * 64 + n * 16 + l16] = O[n] * inv;
  }
  __syncthreads();

  // alpha scatter -> ws [b][u][a][h]  (fully coalesced sequential stores)
  {
    float* ag = ws + WS_ALPHA + (size_t)bid * (NA * H);
    #pragma unroll
    for (int i = 0; i < 4; ++i) {
      int idx = i * 512 + t;
      int a = idx >> 3, hh = idx & 7;
      ag[idx] = sc[a * 9 + hh] * sinv[hh];
    }
  }
  out[(size_t)bid * HID + t] = gu[t] + ws[WS_UBASE + (size_t)bid * HID + t];
}

// ---------------------------------------------------------------------------
// Kernel C: per (b, a-quad). 512 threads = 8 waves (wave = head).
// alpha layout [b][u][a][h]; XCD swizzle groups each batch b on one XCD
// (UT[b] + alpha[b] L2-resident). Pass 1 is 2-deep software-pipelined.
// ---------------------------------------------------------------------------
__global__ __launch_bounds__(512, 4) void ant_kernel(
    const float* __restrict__ edge, float* __restrict__ ws,
    float* __restrict__ out)
{
  const int bid = (blockIdx.x & 7) * 64 + (blockIdx.x >> 3);  // b*64 + aq
  const int b = bid >> 6, a0 = (bid & 63) * 4;
  const int t = threadIdx.x;
  const int w = t >> 6;                // wave = head
  const int lane = t & 63;

  __shared__ float plds[NU * 36];      // 36 KB: [u][h*4 + a], stride 36 (pad)
  __shared__ float galds[4 * H * ED];  // 8 KB : [a][h][e]

  // ---- stage alpha from [b][u][a0..a0+3][h] -> plds[u][h][a] ----
  {
    const float4* ag4 = (const float4*)(ws + WS_ALPHA) +
                        ((size_t)b * NU * NA * H) / 4 + a0 * 2;
    #pragma unroll
    for (int r = 0; r < 4; ++r) {
      int idx4 = r * 512 + t;
      int uu = idx4 >> 3, f = idx4 & 7;     // 8 float4 per u: a=f>>1, hq=f&1
      float4 vv = ag4[(size_t)uu * (NA * H / 4) + f];
      float* dst = plds + uu * 36 + (f & 1) * 16 + (f >> 1);
      dst[0]  = vv.x;
      dst[4]  = vv.y;
      dst[8]  = vv.z;
      dst[12] = vv.w;
    }
  }
  __syncthreads();

  // ---- pass 1: g accumulation, quarter-wave (u_loc, e4), pipelined ----
  const int u_loc = lane >> 4, e4 = lane & 15;
  float4 g[4] = {{0,0,0,0},{0,0,0,0},{0,0,0,0},{0,0,0,0}};

  {
    const float* ebase0 = edge + (((size_t)b * NU) * NA + a0) * ED + e4 * 4;

    // prologue: prefetch u-group 0
    float4 ce0, ce1, ce2, ce3, cp;
    {
      const float* eb = ebase0 + (size_t)u_loc * (NA * ED);
      ce0 = *(const float4*)(eb);
      ce1 = *(const float4*)(eb + ED);
      ce2 = *(const float4*)(eb + 2 * ED);
      ce3 = *(const float4*)(eb + 3 * ED);
      cp  = *(const float4*)(plds + u_loc * 36 + w * 4);
    }

    for (int u0 = 0; u0 < NU; u0 += 4) {
      // prefetch next group (clamped on last iteration; harmless reload)
      const int un = (u0 + 4 < NU ? u0 + 4 : u0) + u_loc;
      const float* eb = ebase0 + (size_t)un * (NA * ED);
      float4 ne0 = *(const float4*)(eb);
      float4 ne1 = *(const float4*)(eb + ED);
      float4 ne2 = *(const float4*)(eb + 2 * ED);
      float4 ne3 = *(const float4*)(eb + 3 * ED);
      float4 np  = *(const float4*)(plds + un * 36 + w * 4);

      g[0].x += cp.x * ce0.x; g[0].y += cp.x * ce0.y; g[0].z += cp.x * ce0.z; g[0].w += cp.x * ce0.w;
      g[1].x += cp.y * ce1.x; g[1].y += cp.y * ce1.y; g[1].z += cp.y * ce1.z; g[1].w += cp.y * ce1.w;
      g[2].x += cp.z * ce2.x; g[2].y += cp.z * ce2.y; g[2].z += cp.z * ce2.z; g[2].w += cp.z * ce2.w;
      g[3].x += cp.w * ce3.x; g[3].y += cp.w * ce3.y; g[3].z += cp.w * ce3.z; g[3].w += cp.w * ce3.w;

      ce0 = ne0; ce1 = ne1; ce2 = ne2; ce3 = ne3; cp = np;
    }
  }
  // merge across quarter-waves (u_loc)
  #pragma unroll
  for (int al = 0; al < 4; ++al) {
    g[al].x += __shfl_xor(g[al].x, 16); g[al].x += __shfl_xor(g[al].x, 32);
    g[al].y += __shfl_xor(g[al].y, 16); g[al].y += __shfl_xor(g[al].y, 32);
    g[al].z += __shfl_xor(g[al].z, 16); g[al].z += __shfl_xor(g[al].z, 32);
    g[al].w += __shfl_xor(g[al].w, 16); g[al].w += __shfl_xor(g[al].w, 32);
  }
  if (u_loc == 0) {
    #pragma unroll
    for (int al = 0; al < 4; ++al)
      *(float4*)(galds + (al * H + w) * ED + e4 * 4) = g[al];
  }

  // ---- pass 2: pu accumulation (thread t = output col j) ----
  float pu[4] = {0.f, 0.f, 0.f, 0.f};
  {
    const float* UTj = ws + WS_UT + ((size_t)b * HID + t) * 256;
    for (int u0 = 0; u0 < NU; u0 += 4) {
      float4 U4 = *(const float4*)(UTj + u0);
      float4 p0 = *(const float4*)(plds + (u0 + 0) * 36 + w * 4);
      float4 p1 = *(const float4*)(plds + (u0 + 1) * 36 + w * 4);
      float4 p2 = *(const float4*)(plds + (u0 + 2) * 36 + w * 4);
      float4 p3 = *(const float4*)(plds + (u0 + 3) * 36 + w * 4);
      pu[0] += p0.x*U4.x + p1.x*U4.y + p2.x*U4.z + p3.x*U4.w;
      pu[1] += p0.y*U4.x + p1.y*U4.y + p2.y*U4.z + p3.y*U4.w;
      pu[2] += p0.z*U4.x + p1.z*U4.y + p2.z*U4.z + p3.z*U4.w;
      pu[3] += p0.w*U4.x + p1.w*U4.y + p2.w*U4.z + p3.w*U4.w;
    }
  }
  __syncthreads();   // galds ready

  // ---- projection + store ----
  {
    const float* wrow = ws + WS_WET32 + (size_t)t * ED;
    float o[4] = {pu[0], pu[1], pu[2], pu[3]};
    for (int e0 = 0; e0 < ED; e0 += 4) {
      float4 wv = *(const float4*)(wrow + e0);
      #pragma unroll
      for (int al = 0; al < 4; ++al) {
        float4 ga4 = *(const float4*)(galds + (al * H + w) * ED + e0);
        o[al] += ga4.x*wv.x + ga4.y*wv.y + ga4.z*wv.z + ga4.w*wv.w;
      }
    }
    float* outa = out + (size_t)(B_ * NU) * HID;
    #pragma unroll
    for (int al = 0; al < 4; ++al)
      outa[(size_t)((b * NA) + a0 + al) * HID + t] = o[al];
  }
}

// ---------------------------------------------------------------------------
extern "C" void kernel_launch(void* const* d_in, const int* in_sizes, int n_in,
                              void* d_out, int out_size, void* d_ws, size_t ws_size,
                              hipStream_t stream) {
  const float* user = (const float*)d_in[0];
  const float* ant  = (const float*)d_in[1];
  const float* edge = (const float*)d_in[2];
  const float* Wu   = (const float*)d_in[3];
  const float* Wa   = (const float*)d_in[4];
  const float* We   = (const float*)d_in[5];
  const float* av   = (const float*)d_in[6];
  const float* Wres = (const float*)d_in[7];
  float* out = (float*)d_out;
  float* ws  = (float*)d_ws;

  prep_kernel<<<dim3(512, 4), 256, 0, stream>>>(user, ant, Wu, Wa, Wres, We, ws);
  score_user_kernel<<<dim3(B_ * NU), 512, 0, stream>>>(edge, av, ws, out);
  ant_kernel<<<dim3(B_ * 64), 512, 0, stream>>>(edge, ws, out);
}